// Round 7
// baseline (131.530 us; speedup 1.0000x reference)
//
#include <hip/hip_runtime.h>
#include <cstddef>
#include <cstdint>

// SupConLoss fused, MFMA + fragment-major loads + bit-packed mask.
//
// Math (row-max cancels exactly):
//   num_i = sum_{j!=i} e^{-adc_ij} D2_j, s_i = sum_{j!=i} e^{-adc_ij}
//   den_i = sum_{j!=i} e^{+adc_ij},      a_i = sum m_ij adc_ij, b_i = sum m_ij
//   D_hat = softmax(0.7*(D2 - num/s) + 0.3*L2); loss = -mean((a - b*log den)/(b+1e-5))
// mask[i][j] = mask[i&2047][j&2047] (labels period 2048) -> bit-packed to 512KB.
//
//   XF[tile16][ks4][lane64][8] : X bf16 fragments (QK A and B operands)
//   DF[jtile64][n8*ks2][lane64][8] : D2^T bf16 fragments (PV B operand)
//   MB[row2048][jt4 8][e 4] : ballot-packed mask bits; word e bit l =
//                             mask[row][jt4*256 + l*4 + e]
// main: 256 thr = 4 waves, wave owns 16 i-rows; all j-tile loads shared
// across waves (L1). P exchange in-register (cvt_pk + shfl). 256-VGPR
// budget (launch_bounds(256,2)) so all per-iter loads stay in flight.

namespace {
constexpr int   kN    = 4096;
constexpr int   kB    = 2048;
constexpr int   kD    = 128;
constexpr float kInvT = 1.0f / 0.07f;
}

typedef __attribute__((ext_vector_type(8))) short bf16x8;
typedef __attribute__((ext_vector_type(4))) float f32x4;
typedef unsigned long long ull;

union U16B { uint4 u; bf16x8 v; };

__device__ __forceinline__ ushort f2bf(float x) {  // RNE f32->bf16 (finite)
    union { float f; uint u; } v; v.f = x;
    return (ushort)((v.u + 0x7FFFu + ((v.u >> 16) & 1u)) >> 16);
}
__device__ __forceinline__ uint pack2(float a, float b) {
    return (uint)f2bf(a) | ((uint)f2bf(b) << 16);
}
__device__ __forceinline__ uint cvtpk(float a, float b) {  // {lo=bf(a), hi=bf(b)}
    uint r;
    asm("v_cvt_pk_bf16_f32 %0, %1, %2" : "=v"(r) : "v"(a), "v"(b));
    return r;
}

// ---- prep: b<64: XF ; b<128: DF ; b<192: MB (ballot bit-pack) ----
__global__ __launch_bounds__(256)
void supcon_prep(const float* __restrict__ feats, const float* __restrict__ Dp,
                 const float* __restrict__ maskp,
                 ushort* __restrict__ XF, ushort* __restrict__ DF,
                 ull* __restrict__ MB)
{
    __shared__ float sh[64][129];
    const int b = blockIdx.x, t = threadIdx.x;
    const int lane = t & 63, l15 = lane & 15, lg = lane >> 4;

    if (b < 64) {
        // XF[tile][ks][lane][8] : row i=tile*16+l15, k=ks*32+lg*8+e
        const int tile = b * 4 + (t >> 6);
        const int i = tile * 16 + l15;
        const float* rp = feats + (size_t)(i & (kB - 1)) * 256 + (i >> 11) * 128;
        #pragma unroll
        for (int ks = 0; ks < 4; ++ks) {
            const float4 v0 = *(const float4*)(rp + ks * 32 + lg * 8);
            const float4 v1 = *(const float4*)(rp + ks * 32 + lg * 8 + 4);
            uint4 u;
            u.x = pack2(v0.x, v0.y); u.y = pack2(v0.z, v0.w);
            u.z = pack2(v1.x, v1.y); u.w = pack2(v1.z, v1.w);
            *(uint4*)&XF[(size_t)tile * 2048 + ks * 512 + lane * 8] = u;
        }
    } else if (b < 128) {
        // DF[jt][(n*2+ks)*64+lane][8] : c=n*16+l15, j=jt*64+ks*32+lg*8+e
        const int jt = b - 64;
        const int r = t >> 2, c0 = (t & 3) * 32;
        const float* dp = Dp + (size_t)((jt * 64 + r) & (kB - 1)) * kD + c0;
        #pragma unroll
        for (int q = 0; q < 8; ++q) {
            const float4 v = *(const float4*)(dp + q * 4);
            sh[r][c0 + q * 4 + 0] = v.x; sh[r][c0 + q * 4 + 1] = v.y;
            sh[r][c0 + q * 4 + 2] = v.z; sh[r][c0 + q * 4 + 3] = v.w;
        }
        __syncthreads();
        #pragma unroll
        for (int k4 = 0; k4 < 4; ++k4) {
            const int U = k4 * 256 + t;
            const int nk = U >> 6;          // 0..15
            const int n = nk >> 1, ks = nk & 1;
            ushort e[8];
            #pragma unroll
            for (int ee = 0; ee < 8; ++ee)
                e[ee] = f2bf(sh[ks * 32 + lg * 8 + ee][n * 16 + l15]);
            uint4 u;
            u.x = (uint)e[0] | ((uint)e[1] << 16);
            u.y = (uint)e[2] | ((uint)e[3] << 16);
            u.z = (uint)e[4] | ((uint)e[5] << 16);
            u.w = (uint)e[6] | ((uint)e[7] << 16);
            *(uint4*)&DF[(size_t)jt * 8192 + (size_t)U * 8] = u;
        }
    } else {
        // MB: 8 rows per wave, 8 groups of 256 j per row, 4 ballots each
        const int wid = (b - 128) * 4 + (t >> 6);   // 0..255
        const int r0 = wid * 8;
        for (int rr = 0; rr < 8; ++rr) {
            const int row = r0 + rr;
            const float* mrow = maskp + (size_t)row * kN;
            #pragma unroll
            for (int j4 = 0; j4 < 8; ++j4) {
                const float4 v = *(const float4*)(mrow + j4 * 256 + lane * 4);
                const ull b0 = __ballot(v.x != 0.f);
                const ull b1 = __ballot(v.y != 0.f);
                const ull b2 = __ballot(v.z != 0.f);
                const ull b3 = __ballot(v.w != 0.f);
                if (lane == 0) {
                    const size_t o = ((size_t)row * 8 + j4) * 4;
                    MB[o + 0] = b0; MB[o + 1] = b1;
                    MB[o + 2] = b2; MB[o + 3] = b3;
                }
            }
        }
    }
}

// ---- main: 256 thr (4 waves x 16 i-rows), fragment-direct coalesced loads ----
__global__ __launch_bounds__(256, 2)
void supcon_main(const ushort* __restrict__ XF,
                 const ushort* __restrict__ DF,
                 const ull* __restrict__ MB,
                 float* __restrict__ num_part,   // [nchunk][4096][128]
                 float* __restrict__ s_part,
                 float* __restrict__ d_part,
                 float* __restrict__ a_part,
                 float* __restrict__ b_part,
                 int jt_per)
{
    __shared__ float SM[4][16][132];

    const int t    = threadIdx.x;
    const int lane = t & 63;
    const int l15  = lane & 15;
    const int lg   = lane >> 4;
    const int w    = t >> 6;
    const int bx   = blockIdx.x;        // 0..63
    const int I0w  = bx * 64 + w * 16;
    const int gi   = I0w + l15;
    const int chunk = blockIdx.y;
    const int Jbase = chunk * (jt_per * 64);

    // bI: B-frags of this wave's 16 i-rows
    bf16x8 bI[4];
    {
        const size_t xfI = (size_t)(bx * 4 + w) * 2048 + lane * 8;
        #pragma unroll
        for (int ks = 0; ks < 4; ++ks)
            bI[ks] = *(const bf16x8*)&XF[xfI + ks * 512];
    }

    f32x4 numacc[8];
    #pragma unroll
    for (int n = 0; n < 8; ++n) numacc[n] = (f32x4){0.f, 0.f, 0.f, 0.f};
    float s_acc = 0.f, d_acc = 0.f, a_acc = 0.f, b_acc = 0.f;

    const int srcA = l15 | (((lg << 1) & 3) << 4);
    const int srcB = l15 | ((((lg << 1) | 1) & 3) << 4);
    const bool hiSel = (lg >= 2);
    const size_t mrowBase = (size_t)(gi & (kB - 1)) * 8;

    const int ngroups = jt_per >> 2;   // 256-j groups
    for (int g = 0; g < ngroups; ++g) {
        const int G0 = Jbase + g * 256;
        // 4 mask words for this 256-j group: word e bit l = mask[gi][G0+l*4+e]
        const size_t mo = (mrowBase + ((G0 & (kB - 1)) >> 8)) * 4;
        const ull mw0 = MB[mo + 0], mw1 = MB[mo + 1];
        const ull mw2 = MB[mo + 2], mw3 = MB[mo + 3];

        #pragma unroll
        for (int q = 0; q < 4; ++q) {
            const int J0 = G0 + q * 64;

            // ---- aJ loads (coalesced XF fragments) ----
            bf16x8 aJ[4][4];
            const size_t xfJ = (size_t)(J0 >> 4) * 2048 + lane * 8;
            #pragma unroll
            for (int m = 0; m < 4; ++m)
                #pragma unroll
                for (int ks = 0; ks < 4; ++ks)
                    aJ[m][ks] = *(const bf16x8*)&XF[xfJ + (size_t)m * 2048 + ks * 512];

            // ---- QK^T (S^T: rows=j, cols=i) ----
            f32x4 acc[4];
            #pragma unroll
            for (int m = 0; m < 4; ++m) acc[m] = (f32x4){0.f, 0.f, 0.f, 0.f};
            #pragma unroll
            for (int ks = 0; ks < 4; ++ks)
                #pragma unroll
                for (int m = 0; m < 4; ++m)
                    acc[m] = __builtin_amdgcn_mfma_f32_16x16x32_bf16(
                        aJ[m][ks], bI[ks], acc[m], 0, 0, 0);

            // ---- issue bD loads (consumed by PV after exp/shfl) ----
            const size_t dfJ = (size_t)(J0 >> 6) * 8192 + lane * 8;
            bf16x8 bD[8][2];
            #pragma unroll
            for (int n = 0; n < 8; ++n)
                #pragma unroll
                for (int ks = 0; ks < 2; ++ks)
                    bD[n][ks] = *(const bf16x8*)&DF[dfJ + (n * 2 + ks) * 512];

            // ---- exp, scalar partials, pack P ----
            const bool isDiag = ((J0 >> 6) == bx);
            uint P[4][2];
            #pragma unroll
            for (int m = 0; m < 4; ++m) {
                float wv4[4];
                #pragma unroll
                for (int r = 0; r < 4; ++r) {
                    // mask bit: word r, bit q*16 + m*4 + lg
                    const ull mwr = (r == 0) ? mw0 : (r == 1) ? mw1
                                  : (r == 2) ? mw2 : mw3;
                    float mm = ((mwr >> (q * 16 + m * 4 + lg)) & 1ull) ? 1.f : 0.f;
                    const float adc = acc[m][r] * kInvT;
                    float wv = __expf(-adc);
                    float pv = __builtin_amdgcn_rcpf(wv);
                    if (isDiag) {
                        const bool nd = ((J0 + m * 16 + lg * 4 + r) != gi);
                        wv = nd ? wv : 0.f;
                        pv = nd ? pv : 0.f;
                        mm = nd ? mm : 0.f;
                    }
                    s_acc += wv;
                    d_acc += pv;
                    a_acc = fmaf(mm, adc, a_acc);
                    b_acc += mm;
                    wv4[r] = wv;
                }
                P[m][0] = cvtpk(wv4[0], wv4[1]);
                P[m][1] = cvtpk(wv4[2], wv4[3]);
            }

            // ---- in-register P redistribution -> PV A-frags ----
            bf16x8 pa[2];
            #pragma unroll
            for (int ks = 0; ks < 2; ++ks) {
                const uint lo0 = (uint)__shfl((int)P[2 * ks][0],     srcA, 64);
                const uint hi0 = (uint)__shfl((int)P[2 * ks + 1][0], srcA, 64);
                const uint lo1 = (uint)__shfl((int)P[2 * ks][1],     srcA, 64);
                const uint hi1 = (uint)__shfl((int)P[2 * ks + 1][1], srcA, 64);
                const uint lo2 = (uint)__shfl((int)P[2 * ks][0],     srcB, 64);
                const uint hi2 = (uint)__shfl((int)P[2 * ks + 1][0], srcB, 64);
                const uint lo3 = (uint)__shfl((int)P[2 * ks][1],     srcB, 64);
                const uint hi3 = (uint)__shfl((int)P[2 * ks + 1][1], srcB, 64);
                U16B u;
                u.u.x = hiSel ? hi0 : lo0;
                u.u.y = hiSel ? hi1 : lo1;
                u.u.z = hiSel ? hi2 : lo2;
                u.u.w = hiSel ? hi3 : lo3;
                pa[ks] = u.v;
            }

            // ---- PV ----
            #pragma unroll
            for (int ks = 0; ks < 2; ++ks)
                #pragma unroll
                for (int n = 0; n < 8; ++n)
                    numacc[n] = __builtin_amdgcn_mfma_f32_16x16x32_bf16(
                        pa[ks], bD[n][ks], numacc[n], 0, 0, 0);

            __builtin_amdgcn_s_barrier();   // phase-lock waves (no data dep)
        }
    }

    // ---- reduce scalars across lg groups ----
    {
        float s = s_acc, d = d_acc, a = a_acc, b = b_acc;
        #pragma unroll
        for (int off = 16; off <= 32; off <<= 1) {
            s += __shfl_xor(s, off, 64);
            d += __shfl_xor(d, off, 64);
            a += __shfl_xor(a, off, 64);
            b += __shfl_xor(b, off, 64);
        }
        if (lane < 16) {
            const size_t o = (size_t)chunk * kN + gi;
            s_part[o] = s; d_part[o] = d; a_part[o] = a; b_part[o] = b;
        }
    }

    // ---- num write: LDS transpose -> contiguous nontemporal 16B stores ----
    #pragma unroll
    for (int n = 0; n < 8; ++n)
        #pragma unroll
        for (int r = 0; r < 4; ++r)
            SM[w][lg * 4 + r][n * 16 + l15] = numacc[n][r];
    const int rhalf = lane >> 5;
    const int c32 = (lane & 31) * 4;
    #pragma unroll
    for (int p = 0; p < 8; ++p) {
        const int row = p * 2 + rhalf;
        const f32x4 v = *(const f32x4*)&SM[w][row][c32];
        __builtin_nontemporal_store(
            v, (f32x4*)&num_part[((size_t)chunk * kN + I0w + row) * kD + c32]);
    }
}

// Kernel B: per-row finish
__global__ __launch_bounds__(256)
void supcon_finish(const float* __restrict__ num_part,
                   const float* __restrict__ s_part,
                   const float* __restrict__ d_part,
                   const float* __restrict__ a_part,
                   const float* __restrict__ b_part,
                   const float* __restrict__ Dp,
                   const float* __restrict__ Lp,
                   float* __restrict__ out,
                   float* __restrict__ mlpp,
                   int jchunks)
{
    const int w    = threadIdx.x >> 6;
    const int lane = threadIdx.x & 63;
    const int row  = blockIdx.x * 4 + w;
    const int c0 = lane, c1 = lane + 64;

    float n0 = 0.f, n1 = 0.f, s = 0.f, den = 0.f, a = 0.f, b = 0.f;
    for (int ch = 0; ch < jchunks; ++ch) {
        const size_t base = ((size_t)ch * kN + row) * 128;
        n0 += num_part[base + c0];
        n1 += num_part[base + c1];
        const int sb = ch * kN + row;
        s   += s_part[sb];
        den += d_part[sb];
        a   += a_part[sb];
        b   += b_part[sb];
    }
    const float* d2 = Dp + (size_t)(row & (kB - 1)) * kD;
    const float* l2 = Lp + (size_t)(row & (kB - 1)) * kD;
    const float inv_s = 1.0f / s;
    float z0 = 0.7f * (d2[c0] - n0 * inv_s) + 0.3f * l2[c0];
    float z1 = 0.7f * (d2[c1] - n1 * inv_s) + 0.3f * l2[c1];

    float mx = fmaxf(z0, z1);
    #pragma unroll
    for (int off = 32; off >= 1; off >>= 1) mx = fmaxf(mx, __shfl_xor(mx, off, 64));
    const float e0 = __expf(z0 - mx);
    const float e1 = __expf(z1 - mx);
    float sm = e0 + e1;
    #pragma unroll
    for (int off = 32; off >= 1; off >>= 1) sm += __shfl_xor(sm, off, 64);
    const float inv = 1.0f / sm;

    out[1 + (size_t)row * kD + c0] = e0 * inv;
    out[1 + (size_t)row * kD + c1] = e1 * inv;

    if (lane == 0)
        mlpp[row] = (a - b * __logf(den)) / (b + 1e-5f);
}

// Kernel C: loss = -mean(mlpp)
__global__ __launch_bounds__(256)
void supcon_loss(const float* __restrict__ mlpp, float* __restrict__ out)
{
    __shared__ float red[4];
    const int t = threadIdx.x;
    float v = 0.f;
    for (int i = t; i < kN; i += 256) v += mlpp[i];
    #pragma unroll
    for (int off = 32; off >= 1; off >>= 1) v += __shfl_xor(v, off, 64);
    if ((t & 63) == 0) red[t >> 6] = v;
    __syncthreads();
    if (t == 0)
        out[0] = -(red[0] + red[1] + red[2] + red[3]) * (1.0f / (float)kN);
}

extern "C" void kernel_launch(void* const* d_in, const int* in_sizes, int n_in,
                              void* d_out, int out_size, void* d_ws, size_t ws_size,
                              hipStream_t stream) {
    const float* feats = (const float*)d_in[0];  // [2048][2][128]
    const float* maskp = (const float*)d_in[1];  // [4096][4096]
    const float* Dp    = (const float*)d_in[2];  // [2048][128]
    const float* Lp    = (const float*)d_in[3];  // [2048][128]
    float* out = (float*)d_out;                  // [0]=loss, [1..]=D_hat

    ushort* XF = (ushort*)d_ws;                           // 1 MB
    ushort* DF = XF + (size_t)kN * kD;                    // 1 MB
    ull*    MB = (ull*)(DF + (size_t)kD * kN);            // 512 KB
    float*  pbase = (float*)(MB + (size_t)kB * 8 * 4);

    auto need = [](int nc) -> size_t {
        return (size_t)kN * kD * 2 * 2                    // XF + DF
             + (size_t)kB * 8 * 4 * 8                     // MB
             + (size_t)nc * kN * kD * 4                   // num partials
             + (size_t)nc * kN * 4 * 4                    // s,d,a,b
             + (size_t)kN * 4;                            // mlpp
    };
    int nchunk = 8;
    while (nchunk > 1 && need(nchunk) > ws_size) nchunk >>= 1;

    float* num_part = pbase;
    float* s_part = num_part + (size_t)nchunk * kN * kD;
    float* d_part = s_part + (size_t)nchunk * kN;
    float* a_part = d_part + (size_t)nchunk * kN;
    float* b_part = a_part + (size_t)nchunk * kN;
    float* mlpp   = b_part + (size_t)nchunk * kN;

    const int jt_per = (kN / 64) / nchunk;

    supcon_prep<<<192, 256, 0, stream>>>(feats, Dp, maskp, XF, DF, MB);
    supcon_main<<<dim3(kN / 64, nchunk), 256, 0, stream>>>(
        XF, DF, MB, num_part, s_part, d_part, a_part, b_part, jt_per);
    supcon_finish<<<kN / 4, 256, 0, stream>>>(
        num_part, s_part, d_part, a_part, b_part, Dp, Lp, out, mlpp, nchunk);
    supcon_loss<<<1, 256, 0, stream>>>(mlpp, out);
}

// Round 8
// 84.022 us; speedup vs baseline: 1.5654x; 1.5654x over previous
//
#include <hip/hip_runtime.h>
#include <cstddef>
#include <cstdint>

// SupConLoss fused, MFMA + fragment-major loads, 32 i-rows/wave, pinned 2 waves/EU.
//
// Math (row-max cancels exactly):
//   num_i = sum_{j!=i} e^{-adc_ij} D2_j, s_i = sum_{j!=i} e^{-adc_ij}
//   den_i = sum_{j!=i} e^{+adc_ij},      a_i = sum m_ij adc_ij, b_i = sum m_ij
//   D_hat = softmax(0.7*(D2 - num/s) + 0.3*L2); loss = -mean((a - b*log den)/(b+1e-5))
// mask[i][j] = mask[i&2047][j&2047] (labels period 2048); mask in {0,1} -> bf16 exact.
//
//   XF[tile16][ks4][lane64][8] : X bf16 fragments (QK A and B operands)
//   DF[jtile64][n8*ks2][lane64][8] : D2^T bf16 fragments (PV B operand)
//   MF[(ti*32+tj)*4+m][lane64][4]  : mask quadrant bf16 fragments
// main: 256 thr = 4 waves; wave owns 32 i-rows (2 subtiles u) -> j-tile
// fragment traffic amortized over 2x rows. amdgpu_waves_per_eu(2,2) pins the
// VGPR budget at 256 so the ~36 loads/iter pipeline without spilling.

namespace {
constexpr int   kN    = 4096;
constexpr int   kB    = 2048;
constexpr int   kD    = 128;
constexpr float kInvT = 1.0f / 0.07f;
}

typedef __attribute__((ext_vector_type(8))) short bf16x8;
typedef __attribute__((ext_vector_type(4))) float f32x4;

union U16B { uint4 u; bf16x8 v; };

__device__ __forceinline__ ushort f2bf(float x) {  // RNE f32->bf16 (finite)
    union { float f; uint u; } v; v.f = x;
    return (ushort)((v.u + 0x7FFFu + ((v.u >> 16) & 1u)) >> 16);
}
__device__ __forceinline__ uint pack2(float a, float b) {
    return (uint)f2bf(a) | ((uint)f2bf(b) << 16);
}
__device__ __forceinline__ uint cvtpk(float a, float b) {  // {lo=bf(a), hi=bf(b)}
    uint r;
    asm("v_cvt_pk_bf16_f32 %0, %1, %2" : "=v"(r) : "v"(a), "v"(b));
    return r;
}
__device__ __forceinline__ float bf2f(ushort u) {
    union { float f; uint x; } v; v.x = (uint)u << 16; return v.f;
}

// ---- prep: b<64: XF ; b<128: DF (LDS transpose) ; b<384: MF ----
__global__ __launch_bounds__(256)
void supcon_prep(const float* __restrict__ feats, const float* __restrict__ Dp,
                 const float* __restrict__ maskp,
                 ushort* __restrict__ XF, ushort* __restrict__ DF,
                 ushort* __restrict__ MF)
{
    __shared__ float sh[64][129];
    const int b = blockIdx.x, t = threadIdx.x;
    const int lane = t & 63, l15 = lane & 15, lg = lane >> 4;

    if (b < 64) {
        const int tile = b * 4 + (t >> 6);
        const int i = tile * 16 + l15;
        const float* rp = feats + (size_t)(i & (kB - 1)) * 256 + (i >> 11) * 128;
        #pragma unroll
        for (int ks = 0; ks < 4; ++ks) {
            const float4 v0 = *(const float4*)(rp + ks * 32 + lg * 8);
            const float4 v1 = *(const float4*)(rp + ks * 32 + lg * 8 + 4);
            uint4 u;
            u.x = pack2(v0.x, v0.y); u.y = pack2(v0.z, v0.w);
            u.z = pack2(v1.x, v1.y); u.w = pack2(v1.z, v1.w);
            *(uint4*)&XF[(size_t)tile * 2048 + ks * 512 + lane * 8] = u;
        }
    } else if (b < 128) {
        const int jt = b - 64;
        const int r = t >> 2, c0 = (t & 3) * 32;
        const float* dp = Dp + (size_t)((jt * 64 + r) & (kB - 1)) * kD + c0;
        #pragma unroll
        for (int q = 0; q < 8; ++q) {
            const float4 v = *(const float4*)(dp + q * 4);
            sh[r][c0 + q * 4 + 0] = v.x; sh[r][c0 + q * 4 + 1] = v.y;
            sh[r][c0 + q * 4 + 2] = v.z; sh[r][c0 + q * 4 + 3] = v.w;
        }
        __syncthreads();
        #pragma unroll
        for (int k4 = 0; k4 < 4; ++k4) {
            const int U = k4 * 256 + t;
            const int nk = U >> 6;
            const int n = nk >> 1, ks = nk & 1;
            ushort e[8];
            #pragma unroll
            for (int ee = 0; ee < 8; ++ee)
                e[ee] = f2bf(sh[ks * 32 + lg * 8 + ee][n * 16 + l15]);
            uint4 u;
            u.x = (uint)e[0] | ((uint)e[1] << 16);
            u.y = (uint)e[2] | ((uint)e[3] << 16);
            u.z = (uint)e[4] | ((uint)e[5] << 16);
            u.w = (uint)e[6] | ((uint)e[7] << 16);
            *(uint4*)&DF[(size_t)jt * 8192 + (size_t)U * 8] = u;
        }
    } else {
        const int pb = b - 128;
        const int g = t >> 6;
        #pragma unroll
        for (int q = 0; q < 4; ++q) {
            const int pair = pb * 16 + g * 4 + q;
            const int ti = pair >> 5, tj = pair & 31;
            #pragma unroll
            for (int m = 0; m < 4; ++m) {
                const float4 v = *(const float4*)(
                    maskp + (size_t)(ti * 16 + l15) * kN + tj * 64 + m * 16 + lg * 4);
                ushort4 u;
                u.x = f2bf(v.x); u.y = f2bf(v.y); u.z = f2bf(v.z); u.w = f2bf(v.w);
                *(ushort4*)&MF[((size_t)(pair * 4 + m) * 64 + lane) * 4] = u;
            }
        }
    }
}

// ---- main: 256 thr = 4 waves x 32 i-rows, 2 waves/EU pinned ----
__global__ __launch_bounds__(256) __attribute__((amdgpu_waves_per_eu(2, 2)))
void supcon_main(const ushort* __restrict__ XF,
                 const ushort* __restrict__ DF,
                 const ushort* __restrict__ MF,
                 float* __restrict__ num_part,   // [nchunk][4096][128]
                 float* __restrict__ s_part,
                 float* __restrict__ d_part,
                 float* __restrict__ a_part,
                 float* __restrict__ b_part,
                 int jt_per)
{
    __shared__ float SM[4][16][132];

    const int t    = threadIdx.x;
    const int lane = t & 63;
    const int l15  = lane & 15;
    const int lg   = lane >> 4;
    const int w    = t >> 6;
    const int bx   = blockIdx.x;        // 0..31  (128-row i-block)
    const int I0w  = bx * 128 + w * 32; // wave's first row
    const int chunk = blockIdx.y;
    const int Jbase = chunk * (jt_per * 64);

    // bI[u][ks]: B-frags of the wave's two 16-row subtiles
    bf16x8 bI[2][4];
    #pragma unroll
    for (int u = 0; u < 2; ++u) {
        const size_t xfI = (size_t)(bx * 8 + w * 2 + u) * 2048 + lane * 8;
        #pragma unroll
        for (int ks = 0; ks < 4; ++ks)
            bI[u][ks] = *(const bf16x8*)&XF[xfI + ks * 512];
    }

    f32x4 numacc[2][8];
    #pragma unroll
    for (int u = 0; u < 2; ++u)
        #pragma unroll
        for (int n = 0; n < 8; ++n)
            numacc[u][n] = (f32x4){0.f, 0.f, 0.f, 0.f};
    float s_acc[2] = {0.f, 0.f}, d_acc[2] = {0.f, 0.f};
    float a_acc[2] = {0.f, 0.f}, b_acc[2] = {0.f, 0.f};

    const int srcA = l15 | (((lg << 1) & 3) << 4);
    const int srcB = l15 | ((((lg << 1) | 1) & 3) << 4);
    const bool hiSel = (lg >= 2);

    // mask prefetch for jt=0
    ushort4 mvn[2][4];
    {
        const int tj = (Jbase & (kB - 1)) >> 6;
        #pragma unroll
        for (int u = 0; u < 2; ++u) {
            const int tiM = ((I0w + u * 16) & (kB - 1)) >> 4;
            #pragma unroll
            for (int m = 0; m < 4; ++m)
                mvn[u][m] = *(const ushort4*)&MF[(((size_t)(tiM * 32 + tj) * 4 + m) * 64 + lane) * 4];
        }
    }

    int J0 = Jbase;
    for (int jt = 0; jt < jt_per; ++jt, J0 += 64) {
        // ---- QK^T with rolling 2-deep aJ; each aJ serves both u ----
        f32x4 acc[2][4];
        #pragma unroll
        for (int u = 0; u < 2; ++u)
            #pragma unroll
            for (int m = 0; m < 4; ++m) acc[u][m] = (f32x4){0.f, 0.f, 0.f, 0.f};
        const size_t xfJ = (size_t)(J0 >> 4) * 2048 + lane * 8;
        bf16x8 aJ2[2][4];
        #pragma unroll
        for (int m = 0; m < 4; ++m)
            aJ2[0][m] = *(const bf16x8*)&XF[xfJ + (size_t)m * 2048];
        #pragma unroll
        for (int ks = 0; ks < 4; ++ks) {
            if (ks < 3) {
                #pragma unroll
                for (int m = 0; m < 4; ++m)
                    aJ2[(ks + 1) & 1][m] =
                        *(const bf16x8*)&XF[xfJ + (size_t)m * 2048 + (ks + 1) * 512];
            }
            #pragma unroll
            for (int m = 0; m < 4; ++m)
                #pragma unroll
                for (int u = 0; u < 2; ++u)
                    acc[u][m] = __builtin_amdgcn_mfma_f32_16x16x32_bf16(
                        aJ2[ks & 1][m], bI[u][ks], acc[u][m], 0, 0, 0);
        }

        // ---- issue bD loads (consumed by PV after exp/shfl) ----
        const size_t dfJ = (size_t)(J0 >> 6) * 8192 + lane * 8;
        bf16x8 bD[8][2];
        #pragma unroll
        for (int n = 0; n < 8; ++n)
            #pragma unroll
            for (int ks = 0; ks < 2; ++ks)
                bD[n][ks] = *(const bf16x8*)&DF[dfJ + (n * 2 + ks) * 512];

        // ---- exp, scalar partials, pack P (per u) ----
        uint P[2][4][2];
        #pragma unroll
        for (int u = 0; u < 2; ++u) {
            const int gi = I0w + u * 16 + l15;
            const bool isDiag = (((I0w + u * 16) >> 6) == (J0 >> 6));
            #pragma unroll
            for (int m = 0; m < 4; ++m) {
                const ushort mmraw[4] = { mvn[u][m].x, mvn[u][m].y,
                                          mvn[u][m].z, mvn[u][m].w };
                float wv4[4];
                #pragma unroll
                for (int r = 0; r < 4; ++r) {
                    const float adc = acc[u][m][r] * kInvT;
                    float wv = __expf(-adc);
                    float pv = __builtin_amdgcn_rcpf(wv);
                    float mm = bf2f(mmraw[r]);
                    if (isDiag) {
                        const bool nd = ((J0 + m * 16 + lg * 4 + r) != gi);
                        wv = nd ? wv : 0.f;
                        pv = nd ? pv : 0.f;
                        mm = nd ? mm : 0.f;
                    }
                    s_acc[u] += wv;
                    d_acc[u] += pv;
                    a_acc[u] = fmaf(mm, adc, a_acc[u]);
                    b_acc[u] += mm;
                    wv4[r] = wv;
                }
                P[u][m][0] = cvtpk(wv4[0], wv4[1]);
                P[u][m][1] = cvtpk(wv4[2], wv4[3]);
            }
        }

        // ---- prefetch next-iter mask ----
        if (jt + 1 < jt_per) {
            const int tj = ((J0 + 64) & (kB - 1)) >> 6;
            #pragma unroll
            for (int u = 0; u < 2; ++u) {
                const int tiM = ((I0w + u * 16) & (kB - 1)) >> 4;
                #pragma unroll
                for (int m = 0; m < 4; ++m)
                    mvn[u][m] = *(const ushort4*)&MF[(((size_t)(tiM * 32 + tj) * 4 + m) * 64 + lane) * 4];
            }
        }

        // ---- in-register P redistribution -> PV A-frags (per u) ----
        bf16x8 pa[2][2];
        #pragma unroll
        for (int u = 0; u < 2; ++u)
            #pragma unroll
            for (int ks = 0; ks < 2; ++ks) {
                const uint lo0 = (uint)__shfl((int)P[u][2 * ks][0],     srcA, 64);
                const uint hi0 = (uint)__shfl((int)P[u][2 * ks + 1][0], srcA, 64);
                const uint lo1 = (uint)__shfl((int)P[u][2 * ks][1],     srcA, 64);
                const uint hi1 = (uint)__shfl((int)P[u][2 * ks + 1][1], srcA, 64);
                const uint lo2 = (uint)__shfl((int)P[u][2 * ks][0],     srcB, 64);
                const uint hi2 = (uint)__shfl((int)P[u][2 * ks + 1][0], srcB, 64);
                const uint lo3 = (uint)__shfl((int)P[u][2 * ks][1],     srcB, 64);
                const uint hi3 = (uint)__shfl((int)P[u][2 * ks + 1][1], srcB, 64);
                U16B uu;
                uu.u.x = hiSel ? hi0 : lo0;
                uu.u.y = hiSel ? hi1 : lo1;
                uu.u.z = hiSel ? hi2 : lo2;
                uu.u.w = hiSel ? hi3 : lo3;
                pa[u][ks] = uu.v;
            }

        // ---- PV ----
        #pragma unroll
        for (int ks = 0; ks < 2; ++ks)
            #pragma unroll
            for (int n = 0; n < 8; ++n)
                #pragma unroll
                for (int u = 0; u < 2; ++u)
                    numacc[u][n] = __builtin_amdgcn_mfma_f32_16x16x32_bf16(
                        pa[u][ks], bD[n][ks], numacc[u][n], 0, 0, 0);

        __builtin_amdgcn_s_barrier();   // phase-lock waves for L1 reuse (no data dep)
    }

    // ---- epilogue per u: scalar reduce + LDS-transposed num stores ----
    #pragma unroll
    for (int u = 0; u < 2; ++u) {
        float s = s_acc[u], d = d_acc[u], a = a_acc[u], b = b_acc[u];
        #pragma unroll
        for (int off = 16; off <= 32; off <<= 1) {
            s += __shfl_xor(s, off, 64);
            d += __shfl_xor(d, off, 64);
            a += __shfl_xor(a, off, 64);
            b += __shfl_xor(b, off, 64);
        }
        if (lane < 16) {
            const size_t o = (size_t)chunk * kN + I0w + u * 16 + lane;
            s_part[o] = s; d_part[o] = d; a_part[o] = a; b_part[o] = b;
        }
    }

    for (int u = 0; u < 2; ++u) {
        #pragma unroll
        for (int n = 0; n < 8; ++n)
            #pragma unroll
            for (int r = 0; r < 4; ++r)
                SM[w][lg * 4 + r][n * 16 + l15] = numacc[u][n][r];
        const int rhalf = lane >> 5;
        const int c32 = (lane & 31) * 4;
        #pragma unroll
        for (int p = 0; p < 8; ++p) {
            const int row = p * 2 + rhalf;
            const f32x4 v = *(const f32x4*)&SM[w][row][c32];
            __builtin_nontemporal_store(
                v, (f32x4*)&num_part[((size_t)chunk * kN + I0w + u * 16 + row) * kD + c32]);
        }
    }
}

// Kernel B: per-row finish
__global__ __launch_bounds__(256)
void supcon_finish(const float* __restrict__ num_part,
                   const float* __restrict__ s_part,
                   const float* __restrict__ d_part,
                   const float* __restrict__ a_part,
                   const float* __restrict__ b_part,
                   const float* __restrict__ Dp,
                   const float* __restrict__ Lp,
                   float* __restrict__ out,
                   float* __restrict__ mlpp,
                   int jchunks)
{
    const int w    = threadIdx.x >> 6;
    const int lane = threadIdx.x & 63;
    const int row  = blockIdx.x * 4 + w;
    const int c0 = lane, c1 = lane + 64;

    float n0 = 0.f, n1 = 0.f, s = 0.f, den = 0.f, a = 0.f, b = 0.f;
    for (int ch = 0; ch < jchunks; ++ch) {
        const size_t base = ((size_t)ch * kN + row) * 128;
        n0 += num_part[base + c0];
        n1 += num_part[base + c1];
        const int sb = ch * kN + row;
        s   += s_part[sb];
        den += d_part[sb];
        a   += a_part[sb];
        b   += b_part[sb];
    }
    const float* d2 = Dp + (size_t)(row & (kB - 1)) * kD;
    const float* l2 = Lp + (size_t)(row & (kB - 1)) * kD;
    const float inv_s = 1.0f / s;
    float z0 = 0.7f * (d2[c0] - n0 * inv_s) + 0.3f * l2[c0];
    float z1 = 0.7f * (d2[c1] - n1 * inv_s) + 0.3f * l2[c1];

    float mx = fmaxf(z0, z1);
    #pragma unroll
    for (int off = 32; off >= 1; off >>= 1) mx = fmaxf(mx, __shfl_xor(mx, off, 64));
    const float e0 = __expf(z0 - mx);
    const float e1 = __expf(z1 - mx);
    float sm = e0 + e1;
    #pragma unroll
    for (int off = 32; off >= 1; off >>= 1) sm += __shfl_xor(sm, off, 64);
    const float inv = 1.0f / sm;

    out[1 + (size_t)row * kD + c0] = e0 * inv;
    out[1 + (size_t)row * kD + c1] = e1 * inv;

    if (lane == 0)
        mlpp[row] = (a - b * __logf(den)) / (b + 1e-5f);
}

// Kernel C: loss = -mean(mlpp)
__global__ __launch_bounds__(256)
void supcon_loss(const float* __restrict__ mlpp, float* __restrict__ out)
{
    __shared__ float red[4];
    const int t = threadIdx.x;
    float v = 0.f;
    for (int i = t; i < kN; i += 256) v += mlpp[i];
    #pragma unroll
    for (int off = 32; off >= 1; off >>= 1) v += __shfl_xor(v, off, 64);
    if ((t & 63) == 0) red[t >> 6] = v;
    __syncthreads();
    if (t == 0)
        out[0] = -(red[0] + red[1] + red[2] + red[3]) * (1.0f / (float)kN);
}

extern "C" void kernel_launch(void* const* d_in, const int* in_sizes, int n_in,
                              void* d_out, int out_size, void* d_ws, size_t ws_size,
                              hipStream_t stream) {
    const float* feats = (const float*)d_in[0];  // [2048][2][128]
    const float* maskp = (const float*)d_in[1];  // [4096][4096]
    const float* Dp    = (const float*)d_in[2];  // [2048][128]
    const float* Lp    = (const float*)d_in[3];  // [2048][128]
    float* out = (float*)d_out;                  // [0]=loss, [1..]=D_hat

    ushort* XF = (ushort*)d_ws;                           // 1 MB
    ushort* DF = XF + (size_t)kN * kD;                    // 1 MB
    ushort* MF = DF + (size_t)kD * kN;                    // 8 MB
    float*  pbase = (float*)(MF + (size_t)kB * kB);

    auto need = [](int nc) -> size_t {
        return (size_t)kN * kD * 2 * 2                    // XF + DF
             + (size_t)kB * kB * 2                        // MF
             + (size_t)nc * kN * kD * 4                   // num partials
             + (size_t)nc * kN * 4 * 4                    // s,d,a,b
             + (size_t)kN * 4;                            // mlpp
    };
    int nchunk = 16;
    while (nchunk > 1 && need(nchunk) > ws_size) nchunk >>= 1;

    float* num_part = pbase;
    float* s_part = num_part + (size_t)nchunk * kN * kD;
    float* d_part = s_part + (size_t)nchunk * kN;
    float* a_part = d_part + (size_t)nchunk * kN;
    float* b_part = a_part + (size_t)nchunk * kN;
    float* mlpp   = b_part + (size_t)nchunk * kN;

    const int jt_per = (kN / 64) / nchunk;

    supcon_prep<<<384, 256, 0, stream>>>(feats, Dp, maskp, XF, DF, MF);
    supcon_main<<<dim3(kN / 128, nchunk), 256, 0, stream>>>(
        XF, DF, MF, num_part, s_part, d_part, a_part, b_part, jt_per);
    supcon_finish<<<kN / 4, 256, 0, stream>>>(
        num_part, s_part, d_part, a_part, b_part, Dp, Lp, out, mlpp, nchunk);
    supcon_loss<<<1, 256, 0, stream>>>(mlpp, out);
}

// Round 9
// 56.696 us; speedup vs baseline: 2.3199x; 1.4820x over previous
//
#include <hip/hip_runtime.h>
#include <cstddef>
#include <cstdint>

// SupConLoss fused, MFMA + fragment-major loads + j-parity wave split.
//
// Math (row-max cancels exactly):
//   num_i = sum_{j!=i} e^{-adc_ij} D2_j, s_i = sum_{j!=i} e^{-adc_ij}
//   den_i = sum_{j!=i} e^{+adc_ij},      a_i = sum m_ij adc_ij, b_i = sum m_ij
//   D_hat = softmax(0.7*(D2 - num/s) + 0.3*L2); loss = -mean((a - b*log den)/(b+1e-5))
// mask[i][j] = mask[i&2047][j&2047] (labels period 2048); mask {0,1} -> bf16 exact.
//
//   XF[tile16][ks4][lane64][8]     : X bf16 fragments (QK A and B operands)
//   DF[jtile64][n8*ks2][lane64][8] : D2^T bf16 fragments (PV B operand)
//   MF[(ti*32+tj)*4+m][lane64][4]  : mask quadrant bf16 fragments
// main: 256 thr = 4 waves = 2 i-subtiles x 2 j-parities; each wave = round-6
// inner loop (rolling aJ, split bD, in-register P exchange) over its parity's
// j-tiles; LDS pairwise reduce merges parities. 2x waves vs round 6 at the
// same workspace footprint -> 4 waves/SIMD latency hiding.

namespace {
constexpr int   kN    = 4096;
constexpr int   kB    = 2048;
constexpr int   kD    = 128;
constexpr float kInvT = 1.0f / 0.07f;
}

typedef __attribute__((ext_vector_type(8))) short bf16x8;
typedef __attribute__((ext_vector_type(4))) float f32x4;

union U16B { uint4 u; bf16x8 v; };

__device__ __forceinline__ ushort f2bf(float x) {  // RNE f32->bf16 (finite)
    union { float f; uint u; } v; v.f = x;
    return (ushort)((v.u + 0x7FFFu + ((v.u >> 16) & 1u)) >> 16);
}
__device__ __forceinline__ uint pack2(float a, float b) {
    return (uint)f2bf(a) | ((uint)f2bf(b) << 16);
}
__device__ __forceinline__ uint cvtpk(float a, float b) {  // {lo=bf(a), hi=bf(b)}
    uint r;
    asm("v_cvt_pk_bf16_f32 %0, %1, %2" : "=v"(r) : "v"(a), "v"(b));
    return r;
}
__device__ __forceinline__ float bf2f(ushort u) {
    union { float f; uint x; } v; v.x = (uint)u << 16; return v.f;
}

// ---- prep: b<64: XF ; b<128: DF (LDS transpose) ; b<384: MF ----
__global__ __launch_bounds__(256)
void supcon_prep(const float* __restrict__ feats, const float* __restrict__ Dp,
                 const float* __restrict__ maskp,
                 ushort* __restrict__ XF, ushort* __restrict__ DF,
                 ushort* __restrict__ MF)
{
    __shared__ float sh[64][129];
    const int b = blockIdx.x, t = threadIdx.x;
    const int lane = t & 63, l15 = lane & 15, lg = lane >> 4;

    if (b < 64) {
        const int tile = b * 4 + (t >> 6);
        const int i = tile * 16 + l15;
        const float* rp = feats + (size_t)(i & (kB - 1)) * 256 + (i >> 11) * 128;
        #pragma unroll
        for (int ks = 0; ks < 4; ++ks) {
            const float4 v0 = *(const float4*)(rp + ks * 32 + lg * 8);
            const float4 v1 = *(const float4*)(rp + ks * 32 + lg * 8 + 4);
            uint4 u;
            u.x = pack2(v0.x, v0.y); u.y = pack2(v0.z, v0.w);
            u.z = pack2(v1.x, v1.y); u.w = pack2(v1.z, v1.w);
            *(uint4*)&XF[(size_t)tile * 2048 + ks * 512 + lane * 8] = u;
        }
    } else if (b < 128) {
        const int jt = b - 64;
        const int r = t >> 2, c0 = (t & 3) * 32;
        const float* dp = Dp + (size_t)((jt * 64 + r) & (kB - 1)) * kD + c0;
        #pragma unroll
        for (int q = 0; q < 8; ++q) {
            const float4 v = *(const float4*)(dp + q * 4);
            sh[r][c0 + q * 4 + 0] = v.x; sh[r][c0 + q * 4 + 1] = v.y;
            sh[r][c0 + q * 4 + 2] = v.z; sh[r][c0 + q * 4 + 3] = v.w;
        }
        __syncthreads();
        #pragma unroll
        for (int k4 = 0; k4 < 4; ++k4) {
            const int U = k4 * 256 + t;
            const int nk = U >> 6;
            const int n = nk >> 1, ks = nk & 1;
            ushort e[8];
            #pragma unroll
            for (int ee = 0; ee < 8; ++ee)
                e[ee] = f2bf(sh[ks * 32 + lg * 8 + ee][n * 16 + l15]);
            uint4 u;
            u.x = (uint)e[0] | ((uint)e[1] << 16);
            u.y = (uint)e[2] | ((uint)e[3] << 16);
            u.z = (uint)e[4] | ((uint)e[5] << 16);
            u.w = (uint)e[6] | ((uint)e[7] << 16);
            *(uint4*)&DF[(size_t)jt * 8192 + (size_t)U * 8] = u;
        }
    } else {
        const int pb = b - 128;
        const int g = t >> 6;
        #pragma unroll
        for (int q = 0; q < 4; ++q) {
            const int pair = pb * 16 + g * 4 + q;
            const int ti = pair >> 5, tj = pair & 31;
            #pragma unroll
            for (int m = 0; m < 4; ++m) {
                const float4 v = *(const float4*)(
                    maskp + (size_t)(ti * 16 + l15) * kN + tj * 64 + m * 16 + lg * 4);
                ushort4 u;
                u.x = f2bf(v.x); u.y = f2bf(v.y); u.z = f2bf(v.z); u.w = f2bf(v.w);
                *(ushort4*)&MF[((size_t)(pair * 4 + m) * 64 + lane) * 4] = u;
            }
        }
    }
}

// ---- main: 256 thr = (2 i-subtiles) x (2 j-parities), 32 i-rows/block ----
__global__ __launch_bounds__(256, 2)
void supcon_main(const ushort* __restrict__ XF,
                 const ushort* __restrict__ DF,
                 const ushort* __restrict__ MF,
                 float* __restrict__ num_part,   // [nchunk][4096][128]
                 float* __restrict__ s_part,
                 float* __restrict__ d_part,
                 float* __restrict__ a_part,
                 float* __restrict__ b_part,
                 int jt_per)                     // must be even
{
    __shared__ float RED[2][16][132];   // cross-parity num reduce     16.9 KB
    __shared__ float SC[2][4][16];      // cross-parity scalar reduce   0.5 KB

    const int t    = threadIdx.x;
    const int lane = t & 63;
    const int l15  = lane & 15;
    const int lg   = lane >> 4;
    const int w    = t >> 6;
    const int ip   = w >> 1;            // i-subtile
    const int jp   = w & 1;             // j-parity
    const int bx   = blockIdx.x;        // 0..127 (32-row i-block)
    const int I0w  = bx * 32 + ip * 16;
    const int gi   = I0w + l15;
    const int chunk = blockIdx.y;
    const int Jbase = chunk * (jt_per * 64);
    const int tiM   = (I0w & (kB - 1)) >> 4;

    // bI: B-frags of this wave's 16 i-rows
    bf16x8 bI[4];
    {
        const size_t xfI = (size_t)(bx * 2 + ip) * 2048 + lane * 8;
        #pragma unroll
        for (int ks = 0; ks < 4; ++ks)
            bI[ks] = *(const bf16x8*)&XF[xfI + ks * 512];
    }

    f32x4 numacc[8];
    #pragma unroll
    for (int n = 0; n < 8; ++n) numacc[n] = (f32x4){0.f, 0.f, 0.f, 0.f};
    float s_acc = 0.f, d_acc = 0.f, a_acc = 0.f, b_acc = 0.f;

    const int srcA = l15 | (((lg << 1) & 3) << 4);
    const int srcB = l15 | ((((lg << 1) | 1) & 3) << 4);
    const bool hiSel = (lg >= 2);

    // mask prefetch for first tile of this parity
    ushort4 mvn[4];
    {
        const int tj = ((Jbase + jp * 64) & (kB - 1)) >> 6;
        #pragma unroll
        for (int m = 0; m < 4; ++m)
            mvn[m] = *(const ushort4*)&MF[(((size_t)(tiM * 32 + tj) * 4 + m) * 64 + lane) * 4];
    }

    for (int jt = jp; jt < jt_per; jt += 2) {
        const int J0 = Jbase + jt * 64;

        // ---- QK^T with rolling 2-deep aJ (coalesced XF loads) ----
        f32x4 acc[4];
        #pragma unroll
        for (int m = 0; m < 4; ++m) acc[m] = (f32x4){0.f, 0.f, 0.f, 0.f};
        const size_t xfJ = (size_t)(J0 >> 4) * 2048 + lane * 8;
        bf16x8 aJ2[2][4];
        #pragma unroll
        for (int m = 0; m < 4; ++m)
            aJ2[0][m] = *(const bf16x8*)&XF[xfJ + (size_t)m * 2048];
        #pragma unroll
        for (int ks = 0; ks < 4; ++ks) {
            if (ks < 3) {
                #pragma unroll
                for (int m = 0; m < 4; ++m)
                    aJ2[(ks + 1) & 1][m] =
                        *(const bf16x8*)&XF[xfJ + (size_t)m * 2048 + (ks + 1) * 512];
            }
            #pragma unroll
            for (int m = 0; m < 4; ++m)
                acc[m] = __builtin_amdgcn_mfma_f32_16x16x32_bf16(
                    aJ2[ks & 1][m], bI[ks], acc[m], 0, 0, 0);
        }

        // ---- issue first-half bD ----
        const size_t dfJ = (size_t)(J0 >> 6) * 8192 + lane * 8;
        bf16x8 bDa[4][2];
        #pragma unroll
        for (int n = 0; n < 4; ++n)
            #pragma unroll
            for (int ks = 0; ks < 2; ++ks)
                bDa[n][ks] = *(const bf16x8*)&DF[dfJ + (n * 2 + ks) * 512];

        // ---- exp, scalar partials, pack P ----
        const bool isDiag = ((J0 >> 6) == (bx >> 1));
        uint P[4][2];
        #pragma unroll
        for (int m = 0; m < 4; ++m) {
            const ushort mmraw[4] = { mvn[m].x, mvn[m].y, mvn[m].z, mvn[m].w };
            float wv4[4];
            #pragma unroll
            for (int r = 0; r < 4; ++r) {
                const float adc = acc[m][r] * kInvT;
                float wv = __expf(-adc);
                float pv = __builtin_amdgcn_rcpf(wv);
                float mm = bf2f(mmraw[r]);
                if (isDiag) {
                    const bool nd = ((J0 + m * 16 + lg * 4 + r) != gi);
                    wv = nd ? wv : 0.f;
                    pv = nd ? pv : 0.f;
                    mm = nd ? mm : 0.f;
                }
                s_acc += wv;
                d_acc += pv;
                a_acc = fmaf(mm, adc, a_acc);
                b_acc += mm;
                wv4[r] = wv;
            }
            P[m][0] = cvtpk(wv4[0], wv4[1]);
            P[m][1] = cvtpk(wv4[2], wv4[3]);
        }

        // ---- prefetch next mask (this parity); issue second-half bD ----
        if (jt + 2 < jt_per) {
            const int tj = ((J0 + 128) & (kB - 1)) >> 6;
            #pragma unroll
            for (int m = 0; m < 4; ++m)
                mvn[m] = *(const ushort4*)&MF[(((size_t)(tiM * 32 + tj) * 4 + m) * 64 + lane) * 4];
        }
        bf16x8 bDb[4][2];
        #pragma unroll
        for (int n = 0; n < 4; ++n)
            #pragma unroll
            for (int ks = 0; ks < 2; ++ks)
                bDb[n][ks] = *(const bf16x8*)&DF[dfJ + ((n + 4) * 2 + ks) * 512];

        // ---- in-register P redistribution -> PV A-frags ----
        bf16x8 pa[2];
        #pragma unroll
        for (int ks = 0; ks < 2; ++ks) {
            const uint lo0 = (uint)__shfl((int)P[2 * ks][0],     srcA, 64);
            const uint hi0 = (uint)__shfl((int)P[2 * ks + 1][0], srcA, 64);
            const uint lo1 = (uint)__shfl((int)P[2 * ks][1],     srcA, 64);
            const uint hi1 = (uint)__shfl((int)P[2 * ks + 1][1], srcA, 64);
            const uint lo2 = (uint)__shfl((int)P[2 * ks][0],     srcB, 64);
            const uint hi2 = (uint)__shfl((int)P[2 * ks + 1][0], srcB, 64);
            const uint lo3 = (uint)__shfl((int)P[2 * ks][1],     srcB, 64);
            const uint hi3 = (uint)__shfl((int)P[2 * ks + 1][1], srcB, 64);
            U16B u;
            u.u.x = hiSel ? hi0 : lo0;
            u.u.y = hiSel ? hi1 : lo1;
            u.u.z = hiSel ? hi2 : lo2;
            u.u.w = hiSel ? hi3 : lo3;
            pa[ks] = u.v;
        }

        // ---- PV ----
        #pragma unroll
        for (int ks = 0; ks < 2; ++ks)
            #pragma unroll
            for (int n = 0; n < 4; ++n)
                numacc[n] = __builtin_amdgcn_mfma_f32_16x16x32_bf16(
                    pa[ks], bDa[n][ks], numacc[n], 0, 0, 0);
        #pragma unroll
        for (int ks = 0; ks < 2; ++ks)
            #pragma unroll
            for (int n = 0; n < 4; ++n)
                numacc[n + 4] = __builtin_amdgcn_mfma_f32_16x16x32_bf16(
                    pa[ks], bDb[n][ks], numacc[n + 4], 0, 0, 0);
    }

    // ---- per-wave scalar reduce across lg groups ----
    float s = s_acc, d = d_acc, a = a_acc, b = b_acc;
    #pragma unroll
    for (int off = 16; off <= 32; off <<= 1) {
        s += __shfl_xor(s, off, 64);
        d += __shfl_xor(d, off, 64);
        a += __shfl_xor(a, off, 64);
        b += __shfl_xor(b, off, 64);
    }

    // ---- cross-parity reduction: jp=1 publishes, jp=0 merges + stores ----
    if (jp == 1) {
        #pragma unroll
        for (int n = 0; n < 8; ++n)
            #pragma unroll
            for (int r = 0; r < 4; ++r)
                RED[ip][lg * 4 + r][n * 16 + l15] = numacc[n][r];
        if (lane < 16) {
            SC[ip][0][lane] = s; SC[ip][1][lane] = d;
            SC[ip][2][lane] = a; SC[ip][3][lane] = b;
        }
    }
    __syncthreads();
    if (jp == 0) {
        if (lane < 16) {
            const size_t o = (size_t)chunk * kN + gi;
            s_part[o] = s + SC[ip][0][lane];
            d_part[o] = d + SC[ip][1][lane];
            a_part[o] = a + SC[ip][2][lane];
            b_part[o] = b + SC[ip][3][lane];
        }
        #pragma unroll
        for (int n = 0; n < 8; ++n)
            #pragma unroll
            for (int r = 0; r < 4; ++r) {
                const float v = numacc[n][r] + RED[ip][lg * 4 + r][n * 16 + l15];
                RED[ip][lg * 4 + r][n * 16 + l15] = v;   // same-wave rewrite
            }
        const int rhalf = lane >> 5;
        const int c32 = (lane & 31) * 4;
        #pragma unroll
        for (int p = 0; p < 8; ++p) {
            const int row = p * 2 + rhalf;
            const f32x4 v = *(const f32x4*)&RED[ip][row][c32];
            __builtin_nontemporal_store(
                v, (f32x4*)&num_part[((size_t)chunk * kN + I0w + row) * kD + c32]);
        }
    }
}

// Kernel B: per-row finish
__global__ __launch_bounds__(256)
void supcon_finish(const float* __restrict__ num_part,
                   const float* __restrict__ s_part,
                   const float* __restrict__ d_part,
                   const float* __restrict__ a_part,
                   const float* __restrict__ b_part,
                   const float* __restrict__ Dp,
                   const float* __restrict__ Lp,
                   float* __restrict__ out,
                   float* __restrict__ mlpp,
                   int jchunks)
{
    const int w    = threadIdx.x >> 6;
    const int lane = threadIdx.x & 63;
    const int row  = blockIdx.x * 4 + w;
    const int c0 = lane, c1 = lane + 64;

    float n0 = 0.f, n1 = 0.f, s = 0.f, den = 0.f, a = 0.f, b = 0.f;
    for (int ch = 0; ch < jchunks; ++ch) {
        const size_t base = ((size_t)ch * kN + row) * 128;
        n0 += num_part[base + c0];
        n1 += num_part[base + c1];
        const int sb = ch * kN + row;
        s   += s_part[sb];
        den += d_part[sb];
        a   += a_part[sb];
        b   += b_part[sb];
    }
    const float* d2 = Dp + (size_t)(row & (kB - 1)) * kD;
    const float* l2 = Lp + (size_t)(row & (kB - 1)) * kD;
    const float inv_s = 1.0f / s;
    float z0 = 0.7f * (d2[c0] - n0 * inv_s) + 0.3f * l2[c0];
    float z1 = 0.7f * (d2[c1] - n1 * inv_s) + 0.3f * l2[c1];

    float mx = fmaxf(z0, z1);
    #pragma unroll
    for (int off = 32; off >= 1; off >>= 1) mx = fmaxf(mx, __shfl_xor(mx, off, 64));
    const float e0 = __expf(z0 - mx);
    const float e1 = __expf(z1 - mx);
    float sm = e0 + e1;
    #pragma unroll
    for (int off = 32; off >= 1; off >>= 1) sm += __shfl_xor(sm, off, 64);
    const float inv = 1.0f / sm;

    out[1 + (size_t)row * kD + c0] = e0 * inv;
    out[1 + (size_t)row * kD + c1] = e1 * inv;

    if (lane == 0)
        mlpp[row] = (a - b * __logf(den)) / (b + 1e-5f);
}

// Kernel C: loss = -mean(mlpp)
__global__ __launch_bounds__(256)
void supcon_loss(const float* __restrict__ mlpp, float* __restrict__ out)
{
    __shared__ float red[4];
    const int t = threadIdx.x;
    float v = 0.f;
    for (int i = t; i < kN; i += 256) v += mlpp[i];
    #pragma unroll
    for (int off = 32; off >= 1; off >>= 1) v += __shfl_xor(v, off, 64);
    if ((t & 63) == 0) red[t >> 6] = v;
    __syncthreads();
    if (t == 0)
        out[0] = -(red[0] + red[1] + red[2] + red[3]) * (1.0f / (float)kN);
}

extern "C" void kernel_launch(void* const* d_in, const int* in_sizes, int n_in,
                              void* d_out, int out_size, void* d_ws, size_t ws_size,
                              hipStream_t stream) {
    const float* feats = (const float*)d_in[0];  // [2048][2][128]
    const float* maskp = (const float*)d_in[1];  // [4096][4096]
    const float* Dp    = (const float*)d_in[2];  // [2048][128]
    const float* Lp    = (const float*)d_in[3];  // [2048][128]
    float* out = (float*)d_out;                  // [0]=loss, [1..]=D_hat

    ushort* XF = (ushort*)d_ws;                           // 1 MB
    ushort* DF = XF + (size_t)kN * kD;                    // 1 MB
    ushort* MF = DF + (size_t)kD * kN;                    // 8 MB
    float*  pbase = (float*)(MF + (size_t)kB * kB);

    auto need = [](int nc) -> size_t {
        return (size_t)kN * kD * 2 * 2                    // XF + DF
             + (size_t)kB * kB * 2                        // MF
             + (size_t)nc * kN * kD * 4                   // num partials
             + (size_t)nc * kN * 4 * 4                    // s,d,a,b
             + (size_t)kN * 4;                            // mlpp
    };
    int nchunk = 16;
    while (nchunk > 1 && need(nchunk) > ws_size) nchunk >>= 1;

    float* num_part = pbase;
    float* s_part = num_part + (size_t)nchunk * kN * kD;
    float* d_part = s_part + (size_t)nchunk * kN;
    float* a_part = d_part + (size_t)nchunk * kN;
    float* b_part = a_part + (size_t)nchunk * kN;
    float* mlpp   = b_part + (size_t)nchunk * kN;

    const int jt_per = (kN / 64) / nchunk;               // even for nchunk<=32

    supcon_prep<<<384, 256, 0, stream>>>(feats, Dp, maskp, XF, DF, MF);
    supcon_main<<<dim3(kN / 32, nchunk), 256, 0, stream>>>(
        XF, DF, MF, num_part, s_part, d_part, a_part, b_part, jt_per);
    supcon_finish<<<kN / 4, 256, 0, stream>>>(
        num_part, s_part, d_part, a_part, b_part, Dp, Lp, out, mlpp, nchunk);
    supcon_loss<<<1, 256, 0, stream>>>(mlpp, out);
}